// Round 8
// baseline (891.614 us; speedup 1.0000x reference)
//
#include <hip/hip_runtime.h>
#include <stdint.h>

#define T_TOK 8192
#define DIM   1024
#define NE    8
#define NH    2816
#define NROWS (T_TOK*2)

typedef __attribute__((ext_vector_type(8))) __bf16 bf16x8;
typedef __attribute__((ext_vector_type(4))) float  f32x4;

typedef __attribute__((address_space(1))) const unsigned int g_as1;
typedef __attribute__((address_space(3))) unsigned int l_as3;
#define GLL(g, l) __builtin_amdgcn_global_load_lds((g_as1*)(g), (l_as3*)(l), 16, 0, 0)
#define MFMA16(a,b,c) __builtin_amdgcn_mfma_f32_16x16x32_bf16(a,b,c,0,0,0)

__device__ __forceinline__ unsigned short f2bf(float f){
  union { float f; uint32_t u; } v; v.f = f;
  uint32_t r = (v.u + 0x7FFFu + ((v.u >> 16) & 1u)) >> 16;
  return (unsigned short)r;
}

// ---------------- init / zero / convert ----------------

__global__ void init_k(int* counts, int* cursor){
  int i = threadIdx.x;
  if (i < NE){ counts[i] = 0; cursor[i] = 0; }
}

__global__ void zero_out_k(float4* __restrict__ out){
  int i = blockIdx.x*blockDim.x + threadIdx.x;
  const int n4 = T_TOK*DIM/4;
  const float4 z = make_float4(0.f,0.f,0.f,0.f);
  for (; i < n4; i += gridDim.x*blockDim.x) out[i] = z;
}

__global__ void cvt_k(const float* __restrict__ x, unsigned short* __restrict__ xbf){
  int i = blockIdx.x*blockDim.x + threadIdx.x;
  const int total = T_TOK*DIM/8;
  for (; i < total; i += gridDim.x*blockDim.x){
    const float4 a = *(const float4*)(x + (size_t)i*8);
    const float4 b = *(const float4*)(x + (size_t)i*8 + 4);
    ushort4 lo = make_ushort4(f2bf(a.x), f2bf(a.y), f2bf(a.z), f2bf(a.w));
    ushort4 hi = make_ushort4(f2bf(b.x), f2bf(b.y), f2bf(b.z), f2bf(b.w));
    *(ushort4*)(xbf + (size_t)i*8)     = lo;
    *(ushort4*)(xbf + (size_t)i*8 + 4) = hi;
  }
}

// transpose-convert: f32 [R][C] -> bf16 [C][R]
__global__ __launch_bounds__(256) void transp_k(const float* __restrict__ in,
    unsigned short* __restrict__ outp, int R, int C)
{
  __shared__ unsigned short Tl[64*68];
  const int r0 = blockIdx.x*64, c0 = blockIdx.y*64;
  const size_t mbase = (size_t)blockIdx.z * (size_t)R * (size_t)C;
  const float* ip = in + mbase;
  unsigned short* op = outp + mbase;
  const int t = threadIdx.x;
  #pragma unroll
  for (int i=0;i<4;i++){
    const int r  = (t>>4) + i*16;
    const int cq = t & 15;
    const float4 v = *(const float4*)(ip + (size_t)(r0+r)*C + c0 + cq*4);
    Tl[(cq*4+0)*68 + r] = f2bf(v.x);
    Tl[(cq*4+1)*68 + r] = f2bf(v.y);
    Tl[(cq*4+2)*68 + r] = f2bf(v.z);
    Tl[(cq*4+3)*68 + r] = f2bf(v.w);
  }
  __syncthreads();
  #pragma unroll
  for (int i=0;i<4;i++){
    const int idx = i*1024 + t*4;
    const int c = idx>>6, r = idx&63;
    const ushort4 v = *(const ushort4*)&Tl[c*68 + r];
    *(ushort4*)(op + (size_t)(c0+c)*R + r0 + r) = v;
  }
}

// fused w1+w3 transpose: z in [0,2*NE)
__global__ __launch_bounds__(256) void transp2_k(const float* __restrict__ w1,
    const float* __restrict__ w3, unsigned short* __restrict__ w1t,
    unsigned short* __restrict__ w3t)
{
  __shared__ unsigned short Tl[64*68];
  const int r0 = blockIdx.x*64, c0 = blockIdx.y*64;
  const int z = blockIdx.z;
  const size_t mbase = (size_t)(z & (NE-1)) * (size_t)DIM * (size_t)NH;
  const float* ip = (z < NE ? w1 : w3) + mbase;
  unsigned short* op = (z < NE ? w1t : w3t) + mbase;
  const int t = threadIdx.x;
  #pragma unroll
  for (int i=0;i<4;i++){
    const int r  = (t>>4) + i*16;
    const int cq = t & 15;
    const float4 v = *(const float4*)(ip + (size_t)(r0+r)*NH + c0 + cq*4);
    Tl[(cq*4+0)*68 + r] = f2bf(v.x);
    Tl[(cq*4+1)*68 + r] = f2bf(v.y);
    Tl[(cq*4+2)*68 + r] = f2bf(v.z);
    Tl[(cq*4+3)*68 + r] = f2bf(v.w);
  }
  __syncthreads();
  #pragma unroll
  for (int i=0;i<4;i++){
    const int idx = i*1024 + t*4;
    const int c = idx>>6, r = idx&63;
    const ushort4 v = *(const ushort4*)&Tl[c*68 + r];
    *(ushort4*)(op + (size_t)(c0+c)*DIM + r0 + r) = v;
  }
}

// ---------------- router ----------------

__global__ void router_k(const float* __restrict__ x, const float* __restrict__ rw,
                         int* __restrict__ topk_e, float* __restrict__ topk_w,
                         int* __restrict__ counts){
  const int t = blockIdx.x;
  const int l = threadIdx.x;
  const float* xr = x + (size_t)t * DIM;
  float acc[NE];
  #pragma unroll
  for (int e=0;e<NE;e++) acc[e] = 0.f;
  #pragma unroll
  for (int i=0;i<DIM/64;i++){
    float xv = xr[l + 64*i];
    #pragma unroll
    for (int e=0;e<NE;e++) acc[e] += xv * rw[e*DIM + l + 64*i];
  }
  #pragma unroll
  for (int e=0;e<NE;e++){
    float v = acc[e];
    #pragma unroll
    for (int off=32; off; off>>=1) v += __shfl_xor(v, off);
    acc[e] = v;
  }
  if (l == 0){
    int e0 = 0; float v0 = acc[0];
    #pragma unroll
    for (int e=1;e<NE;e++) if (acc[e] > v0){ v0 = acc[e]; e0 = e; }
    int e1 = -1; float v1 = -1e30f;
    #pragma unroll
    for (int e=0;e<NE;e++) if (e != e0 && acc[e] > v1){ v1 = acc[e]; e1 = e; }
    float ex = __expf(v1 - v0);
    float s  = 1.f + ex;
    topk_e[t*2]   = e0;  topk_e[t*2+1] = e1;
    topk_w[t*2]   = 1.f/s; topk_w[t*2+1] = ex/s;
    atomicAdd(&counts[e0], 1);
    atomicAdd(&counts[e1], 1);
  }
}

__global__ void prefix_k(const int* __restrict__ counts, int* __restrict__ offs){
  if (threadIdx.x == 0 && blockIdx.x == 0){
    int s = 0;
    for (int e=0;e<NE;e++){ offs[e] = s; s += counts[e]; }
  }
}

__global__ void scatter_k(const int* __restrict__ topk_e, const float* __restrict__ topk_w,
                          const int* __restrict__ offs, int* __restrict__ cursor,
                          int* __restrict__ row_tok, float* __restrict__ row_w){
  int t = blockIdx.x*blockDim.x + threadIdx.x;
  if (t >= T_TOK) return;
  #pragma unroll
  for (int k=0;k<2;k++){
    int e = topk_e[t*2+k];
    int p = atomicAdd(&cursor[e], 1);
    int flat = offs[e] + p;
    row_tok[flat] = t;
    row_w[flat]   = topk_w[t*2+k];
  }
}

// ============ FAST GEMMs: big-tile ring-2, counted vmcnt, swizzle, L2 grid ============
// Both keep LDS small enough for 2 blocks/CU (the empirically-required TLP).
// Swizzle (BK=32): chunk ^= (row>>1)&3 on GLL source + ds_read (0 conflicts, r6-verified).

// GEMM1: h = silu(X@W1)*(X@W3). BM=256, BN=128 per matrix, BK=32. LDS 64 KB.
__global__ __launch_bounds__(512,2) void gemm1_q(
    const unsigned short* __restrict__ xbf,
    const unsigned short* __restrict__ w1t, const unsigned short* __restrict__ w3t,
    unsigned short* __restrict__ hbuf,
    const int* __restrict__ row_tok,
    const int* __restrict__ counts, const int* __restrict__ offs)
{
  __shared__ unsigned short As [2][256*32];   // 32 KB
  __shared__ unsigned short B1s[2][128*32];   // 16 KB
  __shared__ unsigned short B3s[2][128*32];   // 16 KB

  // locality grid: lids (e, h-tile, rb), chunk 1408 = one expert per XCD
  const int i   = blockIdx.y*64 + blockIdx.x;     // grid (64,176)
  const int lid = (i & 7)*1408 + (i >> 3);
  const int e   = lid / 1408;
  const int rem = lid - e*1408;
  const int h0  = (rem >> 6) * 128;               // 22 h-tiles
  const int rb  = rem & 63;

  const int cnt  = counts[e];
  const int row0 = rb * 256;
  if (row0 >= cnt) return;
  const int nv   = min(256, cnt - row0);
  const int base = offs[e] + row0;
  const int NK   = DIM/32;                        // 32

  const int t = threadIdx.x;
  const int r_loc = t >> 2, sct = t & 3;
  const int csw = (sct ^ ((r_loc >> 1) & 3)) * 8;   // same for r_loc+128 (128%8==0)
  const int tokA = row_tok[base + min(r_loc,       nv-1)];
  const int tokB = row_tok[base + min(r_loc + 128, nv-1)];
  const unsigned short* aP0 = xbf + (size_t)tokA*DIM + csw;
  const unsigned short* aP1 = xbf + (size_t)tokB*DIM + csw;
  const unsigned short* b1S = w1t + ((size_t)(e*NH + h0) + r_loc)*DIM + csw;
  const unsigned short* b3S = w3t + ((size_t)(e*NH + h0) + r_loc)*DIM + csw;
  const int lo = t*16;

  const int wid = t >> 6, l = t & 63;
  const int wr = wid >> 2, wc = wid & 3;          // 2M x 4N; wave = 128 rows x 32 cols/mat
  const int lr = l & 15,  lk = l >> 4;

  f32x4 acc1[8][2], acc3[8][2];                   // 128 AGPR
  #pragma unroll
  for (int m=0;m<8;m++)
    #pragma unroll
    for (int n=0;n<2;n++){ acc1[m][n] = (f32x4)0.f; acc3[m][n] = (f32x4)0.f; }

  // prologue: stage tile 0 (4 GLL)
  GLL(aP0, (char*)As[0] + lo); GLL(aP1, (char*)As[0] + 8192 + lo);
  GLL(b1S, (char*)B1s[0] + lo); GLL(b3S, (char*)B3s[0] + lo);

  for (int kt=0; kt<NK; ++kt){
    const int cur = kt & 1;
    if (kt+1 < NK){
      const int k1 = (kt+1)*32;
      GLL(aP0+k1, (char*)As[cur^1] + lo); GLL(aP1+k1, (char*)As[cur^1] + 8192 + lo);
      GLL(b1S+k1, (char*)B1s[cur^1] + lo); GLL(b3S+k1, (char*)B3s[cur^1] + lo);
      asm volatile("s_waitcnt vmcnt(4)" ::: "memory");   // retire tile kt, keep kt+1 in flight
    } else {
      asm volatile("s_waitcnt vmcnt(0)" ::: "memory");
    }
    __builtin_amdgcn_s_barrier();

    const unsigned short* Ab  = As [cur];
    const unsigned short* B1b = B1s[cur];
    const unsigned short* B3b = B3s[cur];

    bf16x8 a[8], b1[2], b3[2];
    #pragma unroll
    for (int m=0;m<8;m++){
      const int row = wr*128 + m*16 + lr;
      a[m] = *(const bf16x8*)&Ab[row*32 + ((lk ^ ((row>>1)&3))<<3)];
    }
    #pragma unroll
    for (int n=0;n<2;n++){
      const int row = wc*32 + n*16 + lr;
      const int off = row*32 + ((lk ^ ((row>>1)&3))<<3);
      b1[n] = *(const bf16x8*)&B1b[off];
      b3[n] = *(const bf16x8*)&B3b[off];
    }
    __builtin_amdgcn_s_setprio(1);
    #pragma unroll
    for (int m=0;m<8;m++)
      #pragma unroll
      for (int n=0;n<2;n++){
        acc1[m][n] = MFMA16(a[m], b1[n], acc1[m][n]);
        acc3[m][n] = MFMA16(a[m], b3[n], acc3[m][n]);
      }
    __builtin_amdgcn_s_setprio(0);
    __builtin_amdgcn_s_barrier();
  }

  #pragma unroll
  for (int m=0;m<8;m++){
    #pragma unroll
    for (int i2=0;i2<4;i2++){
      const int r = wr*128 + m*16 + lk*4 + i2;
      if (r < nv){
        const size_t rowbase = (size_t)(base + r) * NH;
        #pragma unroll
        for (int n=0;n<2;n++){
          float z  = acc1[m][n][i2];
          float p3 = acc3[m][n][i2];
          float hv = (z / (1.f + __expf(-z))) * p3;
          hbuf[rowbase + h0 + wc*32 + n*16 + lr] = f2bf(hv);
        }
      }
    }
  }
}

// GEMM2: out += rw*(H@W2). BM=128, BN=256, BK=32. LDS 48 KB.
__global__ __launch_bounds__(512,2) void gemm2_q(
    const unsigned short* __restrict__ hbuf,
    const unsigned short* __restrict__ w2t,
    float* __restrict__ out,
    const int* __restrict__ row_tok, const float* __restrict__ row_w,
    const int* __restrict__ counts, const int* __restrict__ offs)
{
  __shared__ unsigned short As[2][128*32];   // 16 KB
  __shared__ unsigned short Bs[2][256*32];   // 32 KB

  // locality grid: lids (e, d-tile, rb), chunk 256 = one expert per XCD
  const int i   = blockIdx.y*64 + blockIdx.x;     // grid (64,32)
  const int lid = (i & 7)*256 + (i >> 3);
  const int e   = lid >> 8;
  const int rem = lid & 255;
  const int d0  = (rem >> 6) * 256;               // 4 d-tiles
  const int rb  = rem & 63;

  const int cnt  = counts[e];
  const int row0 = rb * 128;
  if (row0 >= cnt) return;
  const int nv   = min(128, cnt - row0);
  const int base = offs[e] + row0;
  const int NK   = NH/32;                         // 88

  const int t = threadIdx.x;
  const int r_loc = t >> 2, sct = t & 3;
  const int csw = (sct ^ ((r_loc >> 1) & 3)) * 8;
  const unsigned short* aS  = hbuf + (size_t)(base + min(r_loc, nv-1))*NH + csw;
  const unsigned short* bS0 = w2t + ((size_t)(e*DIM + d0) + r_loc)*NH + csw;
  const unsigned short* bS1 = bS0 + (size_t)128*NH;
  const int lo = t*16;

  const int wid = t >> 6, l = t & 63;
  const int wr = wid >> 2, wc = wid & 3;          // wave = 64 rows x 64 cols
  const int lr = l & 15,  lk = l >> 4;

  f32x4 acc[4][4];                                // 64 AGPR
  #pragma unroll
  for (int m=0;m<4;m++)
    #pragma unroll
    for (int n=0;n<4;n++) acc[m][n] = (f32x4)0.f;

  GLL(aS,  (char*)As[0] + lo);
  GLL(bS0, (char*)Bs[0] + lo); GLL(bS1, (char*)Bs[0] + 8192 + lo);

  for (int kt=0; kt<NK; ++kt){
    const int cur = kt & 1;
    if (kt+1 < NK){
      const int k1 = (kt+1)*32;
      GLL(aS+k1,  (char*)As[cur^1] + lo);
      GLL(bS0+k1, (char*)Bs[cur^1] + lo); GLL(bS1+k1, (char*)Bs[cur^1] + 8192 + lo);
      asm volatile("s_waitcnt vmcnt(3)" ::: "memory");
    } else {
      asm volatile("s_waitcnt vmcnt(0)" ::: "memory");
    }
    __builtin_amdgcn_s_barrier();

    const unsigned short* Ab = As[cur];
    const unsigned short* Bb = Bs[cur];

    bf16x8 a[4], b[4];
    #pragma unroll
    for (int m=0;m<4;m++){
      const int row = wr*64 + m*16 + lr;
      a[m] = *(const bf16x8*)&Ab[row*32 + ((lk ^ ((row>>1)&3))<<3)];
    }
    #pragma unroll
    for (int n=0;n<4;n++){
      const int row = wc*64 + n*16 + lr;
      b[n] = *(const bf16x8*)&Bb[row*32 + ((lk ^ ((row>>1)&3))<<3)];
    }
    __builtin_amdgcn_s_setprio(1);
    #pragma unroll
    for (int m=0;m<4;m++)
      #pragma unroll
      for (int n=0;n<4;n++)
        acc[m][n] = MFMA16(a[m], b[n], acc[m][n]);
    __builtin_amdgcn_s_setprio(0);
    __builtin_amdgcn_s_barrier();
  }

  #pragma unroll
  for (int m=0;m<4;m++){
    #pragma unroll
    for (int i2=0;i2<4;i2++){
      const int r = wr*64 + m*16 + lk*4 + i2;
      if (r < nv){
        const int flat = base + r;
        const int tok  = row_tok[flat];
        const float wgt = row_w[flat];
        float* orow = out + (size_t)tok * DIM + d0 + wc*64;
        #pragma unroll
        for (int n=0;n<4;n++)
          atomicAdd(&orow[n*16 + lr], acc[m][n][i2] * wgt);
      }
    }
  }
}

// ============ SLOW FALLBACK (f32 weights, small ws) ============

__global__ __launch_bounds__(256) void gemm1_k(
    const unsigned short* __restrict__ xbf,
    const float* __restrict__ w1, const float* __restrict__ w3,
    unsigned short* __restrict__ hbuf,
    const int* __restrict__ row_tok,
    const int* __restrict__ counts, const int* __restrict__ offs)
{
  __shared__ unsigned short Al [128*32];
  __shared__ unsigned short B1l[128*32];
  __shared__ unsigned short B3l[128*32];
  const int e   = blockIdx.y >> 6;
  const int rb  = blockIdx.y & 63;
  const int cnt = counts[e];
  const int row0 = rb * 128;
  if (row0 >= cnt) return;
  const int nv   = min(128, cnt - row0);
  const int base = offs[e] + row0;
  const int h0   = blockIdx.x * 128;
  const int t  = threadIdx.x;
  const int ar0 = t >> 2;
  const int ac  = t & 3;
  const int tok0 = row_tok[base + min(ar0,      nv-1)];
  const int tok1 = row_tok[base + min(ar0 + 64, nv-1)];
  const size_t asrc0 = (size_t)tok0 * DIM + ac*8;
  const size_t asrc1 = (size_t)tok1 * DIM + ac*8;
  const int dg = t >> 5;
  const int hq = t & 31;
  const float* w1p = w1 + (size_t)e * DIM * NH + (size_t)(h0 + hq*4);
  const float* w3p = w3 + (size_t)e * DIM * NH + (size_t)(h0 + hq*4);
  const int wid = t >> 6, l = t & 63;
  const int wr = wid >> 1, wc = wid & 1;
  const int lr = l & 15,  lk = l >> 4;
  f32x4 acc1[4][4], acc3[4][4];
  #pragma unroll
  for (int m=0;m<4;m++)
    #pragma unroll
    for (int n=0;n<4;n++){ acc1[m][n] = (f32x4)0.f; acc3[m][n] = (f32x4)0.f; }
  for (int kk=0; kk<DIM/32; ++kk){
    const int k0 = kk*32;
    __syncthreads();
    *(uint4*)&Al[ar0*32 + ac*8]      = *(const uint4*)(xbf + asrc0 + k0);
    *(uint4*)&Al[(ar0+64)*32 + ac*8] = *(const uint4*)(xbf + asrc1 + k0);
    {
      const float4 f0 = *(const float4*)(w1p + (size_t)(k0 + dg*4 + 0)*NH);
      const float4 f1 = *(const float4*)(w1p + (size_t)(k0 + dg*4 + 1)*NH);
      const float4 f2 = *(const float4*)(w1p + (size_t)(k0 + dg*4 + 2)*NH);
      const float4 f3 = *(const float4*)(w1p + (size_t)(k0 + dg*4 + 3)*NH);
      const float* p0=(const float*)&f0; const float* p1=(const float*)&f1;
      const float* p2=(const float*)&f2; const float* p3=(const float*)&f3;
      #pragma unroll
      for (int j=0;j<4;j++){
        ushort4 pk = make_ushort4(f2bf(p0[j]), f2bf(p1[j]), f2bf(p2[j]), f2bf(p3[j]));
        *(ushort4*)&B1l[(hq*4+j)*32 + dg*4] = pk;
      }
      const float4 g0 = *(const float4*)(w3p + (size_t)(k0 + dg*4 + 0)*NH);
      const float4 g1 = *(const float4*)(w3p + (size_t)(k0 + dg*4 + 1)*NH);
      const float4 g2 = *(const float4*)(w3p + (size_t)(k0 + dg*4 + 2)*NH);
      const float4 g3 = *(const float4*)(w3p + (size_t)(k0 + dg*4 + 3)*NH);
      const float* q0=(const float*)&g0; const float* q1=(const float*)&g1;
      const float* q2=(const float*)&g2; const float* q3=(const float*)&g3;
      #pragma unroll
      for (int j=0;j<4;j++){
        ushort4 pk = make_ushort4(f2bf(q0[j]), f2bf(q1[j]), f2bf(q2[j]), f2bf(q3[j]));
        *(ushort4*)&B3l[(hq*4+j)*32 + dg*4] = pk;
      }
    }
    __syncthreads();
    bf16x8 a[4], b1[4], b3[4];
    #pragma unroll
    for (int m=0;m<4;m++) a[m] = *(const bf16x8*)&Al[(wr*64 + m*16 + lr)*32 + lk*8];
    #pragma unroll
    for (int n=0;n<4;n++){
      b1[n] = *(const bf16x8*)&B1l[(wc*64 + n*16 + lr)*32 + lk*8];
      b3[n] = *(const bf16x8*)&B3l[(wc*64 + n*16 + lr)*32 + lk*8];
    }
    #pragma unroll
    for (int m=0;m<4;m++)
      #pragma unroll
      for (int n=0;n<4;n++){
        acc1[m][n] = MFMA16(a[m], b1[n], acc1[m][n]);
        acc3[m][n] = MFMA16(a[m], b3[n], acc3[m][n]);
      }
  }
  #pragma unroll
  for (int m=0;m<4;m++){
    #pragma unroll
    for (int i=0;i<4;i++){
      const int r = wr*64 + m*16 + lk*4 + i;
      if (r < nv){
        const size_t rowbase = (size_t)(base + r) * NH;
        #pragma unroll
        for (int n=0;n<4;n++){
          float z  = acc1[m][n][i];
          float p3 = acc3[m][n][i];
          float hv = (z / (1.f + __expf(-z))) * p3;
          hbuf[rowbase + h0 + wc*64 + n*16 + lr] = f2bf(hv);
        }
      }
    }
  }
}

__global__ __launch_bounds__(256) void gemm2_k(
    const unsigned short* __restrict__ hbuf,
    const float* __restrict__ w2,
    float* __restrict__ out,
    const int* __restrict__ row_tok, const float* __restrict__ row_w,
    const int* __restrict__ counts, const int* __restrict__ offs)
{
  __shared__ unsigned short Al[128*32];
  __shared__ unsigned short Bl[128*32];
  const int e   = blockIdx.y >> 6;
  const int rb  = blockIdx.y & 63;
  const int cnt = counts[e];
  const int row0 = rb * 128;
  if (row0 >= cnt) return;
  const int nv   = min(128, cnt - row0);
  const int base = offs[e] + row0;
  const int d0   = blockIdx.x * 128;
  const int t  = threadIdx.x;
  const int ar0 = t >> 2;
  const int ac  = t & 3;
  const size_t asrc0 = (size_t)(base + min(ar0,      nv-1)) * NH + ac*8;
  const size_t asrc1 = (size_t)(base + min(ar0 + 64, nv-1)) * NH + ac*8;
  const int dg = t >> 5;
  const int hq = t & 31;
  const float* w2p = w2 + (size_t)e * NH * DIM + (size_t)(d0 + hq*4);
  const int wid = t >> 6, l = t & 63;
  const int wr = wid >> 1, wc = wid & 1;
  const int lr = l & 15,  lk = l >> 4;
  f32x4 acc[4][4];
  #pragma unroll
  for (int m=0;m<4;m++)
    #pragma unroll
    for (int n=0;n<4;n++) acc[m][n] = (f32x4)0.f;
  for (int kk=0; kk<NH/32; ++kk){
    const int k0 = kk*32;
    __syncthreads();
    *(uint4*)&Al[ar0*32 + ac*8]      = *(const uint4*)(hbuf + asrc0 + k0);
    *(uint4*)&Al[(ar0+64)*32 + ac*8] = *(const uint4*)(hbuf + asrc1 + k0);
    {
      const float4 f0 = *(const float4*)(w2p + (size_t)(k0 + dg*4 + 0)*DIM);
      const float4 f1 = *(const float4*)(w2p + (size_t)(k0 + dg*4 + 1)*DIM);
      const float4 f2 = *(const float4*)(w2p + (size_t)(k0 + dg*4 + 2)*DIM);
      const float4 f3 = *(const float4*)(w2p + (size_t)(k0 + dg*4 + 3)*DIM);
      const float* p0=(const float*)&f0; const float* p1=(const float*)&f1;
      const float* p2=(const float*)&f2; const float* p3=(const float*)&f3;
      #pragma unroll
      for (int j=0;j<4;j++){
        ushort4 pk = make_ushort4(f2bf(p0[j]), f2bf(p1[j]), f2bf(p2[j]), f2bf(p3[j]));
        *(ushort4*)&Bl[(hq*4+j)*32 + dg*4] = pk;
      }
    }
    __syncthreads();
    bf16x8 a[4], b[4];
    #pragma unroll
    for (int m=0;m<4;m++) a[m] = *(const bf16x8*)&Al[(wr*64 + m*16 + lr)*32 + lk*8];
    #pragma unroll
    for (int n=0;n<4;n++)  b[n] = *(const bf16x8*)&Bl[(wc*64 + n*16 + lr)*32 + lk*8];
    #pragma unroll
    for (int m=0;m<4;m++)
      #pragma unroll
      for (int n=0;n<4;n++)
        acc[m][n] = MFMA16(a[m], b[n], acc[m][n]);
  }
  #pragma unroll
  for (int m=0;m<4;m++){
    #pragma unroll
    for (int i=0;i<4;i++){
      const int r = wr*64 + m*16 + lk*4 + i;
      if (r < nv){
        const int flat = base + r;
        const int tok  = row_tok[flat];
        const float wgt = row_w[flat];
        float* orow = out + (size_t)tok * DIM + d0 + wc*64;
        #pragma unroll
        for (int n=0;n<4;n++)
          atomicAdd(&orow[n*16 + lr], acc[m][n][i] * wgt);
      }
    }
  }
}

// ---------------- launch ----------------

extern "C" void kernel_launch(void* const* d_in, const int* in_sizes, int n_in,
                              void* d_out, int out_size, void* d_ws, size_t ws_size,
                              hipStream_t stream) {
  (void)in_sizes; (void)n_in; (void)out_size;
  const float* x   = (const float*)d_in[0];
  const float* rw  = (const float*)d_in[1];
  const float* w1  = (const float*)d_in[2];
  const float* w2  = (const float*)d_in[3];
  const float* w3  = (const float*)d_in[4];
  float* out = (float*)d_out;
  char* ws = (char*)d_ws;

  const size_t SZ_XBF  = (size_t)T_TOK*DIM*2;
  const size_t SZ_HBUF = (size_t)NROWS*NH*2;
  const size_t SZ_WT   = (size_t)NE*NH*DIM*2;
  const size_t SZ_SMALL = (size_t)NROWS*4*2 + (size_t)T_TOK*2*4*2 + 3*64*4 + 4096;
  const size_t NEED_FAST = SZ_XBF + SZ_HBUF + 2*SZ_WT + SZ_SMALL;

  if (ws_size >= NEED_FAST) {
    size_t off = 0;
    unsigned short* xbf  = (unsigned short*)(ws + off); off += SZ_XBF;
    unsigned short* hbuf = (unsigned short*)(ws + off); off += SZ_HBUF;
    unsigned short* w1t  = (unsigned short*)(ws + off); off += SZ_WT;
    unsigned short* w3t  = (unsigned short*)(ws + off); off += SZ_WT;
    unsigned short* w2t  = w1t;  // w2t overlays w1t (dead after gemm1)
    int*   row_tok = (int*)  (ws + off); off += NROWS*4;
    float* row_w   = (float*)(ws + off); off += NROWS*4;
    int*   topk_e  = (int*)  (ws + off); off += T_TOK*2*4;
    float* topk_w  = (float*)(ws + off); off += T_TOK*2*4;
    int*   counts  = (int*)  (ws + off); off += 64;
    int*   offs    = (int*)  (ws + off); off += 64;
    int*   cursor  = (int*)  (ws + off); off += 64;

    init_k    <<<1, 64, 0, stream>>>(counts, cursor);
    zero_out_k<<<2048, 256, 0, stream>>>((float4*)out);
    cvt_k     <<<2048, 256, 0, stream>>>(x, xbf);
    router_k  <<<T_TOK, 64, 0, stream>>>(x, rw, topk_e, topk_w, counts);
    prefix_k  <<<1, 64, 0, stream>>>(counts, offs);
    scatter_k <<<(T_TOK+255)/256, 256, 0, stream>>>(topk_e, topk_w, offs, cursor, row_tok, row_w);
    transp2_k <<<dim3(DIM/64, NH/64, 2*NE), 256, 0, stream>>>(w1, w3, w1t, w3t);
    gemm1_q   <<<dim3(64, 176), 512, 0, stream>>>(xbf, w1t, w3t, hbuf, row_tok, counts, offs);
    transp_k  <<<dim3(NH/64, DIM/64, NE), 256, 0, stream>>>(w2, w2t, NH, DIM);
    gemm2_q   <<<dim3(64, 32), 512, 0, stream>>>(hbuf, w2t, out, row_tok, row_w, counts, offs);
  } else {
    size_t off = 0;
    unsigned short* xbf  = (unsigned short*)(ws + off); off += SZ_XBF;
    unsigned short* hbuf = (unsigned short*)(ws + off); off += SZ_HBUF;
    int*   row_tok = (int*)  (ws + off); off += NROWS*4;
    float* row_w   = (float*)(ws + off); off += NROWS*4;
    int*   topk_e  = (int*)  (ws + off); off += T_TOK*2*4;
    float* topk_w  = (float*)(ws + off); off += T_TOK*2*4;
    int*   counts  = (int*)  (ws + off); off += 64;
    int*   offs    = (int*)  (ws + off); off += 64;
    int*   cursor  = (int*)  (ws + off); off += 64;

    init_k    <<<1, 64, 0, stream>>>(counts, cursor);
    zero_out_k<<<2048, 256, 0, stream>>>((float4*)out);
    cvt_k     <<<2048, 256, 0, stream>>>(x, xbf);
    router_k  <<<T_TOK, 64, 0, stream>>>(x, rw, topk_e, topk_w, counts);
    prefix_k  <<<1, 64, 0, stream>>>(counts, offs);
    scatter_k <<<(T_TOK+255)/256, 256, 0, stream>>>(topk_e, topk_w, offs, cursor, row_tok, row_w);
    gemm1_k   <<<dim3(NH/128, NE*64), 256, 0, stream>>>(xbf, w1, w3, hbuf, row_tok, counts, offs);
    gemm2_k   <<<dim3(DIM/128, NE*64), 256, 0, stream>>>(hbuf, w2, out, row_tok, row_w, counts, offs);
  }
}

// Round 9
// 827.740 us; speedup vs baseline: 1.0772x; 1.0772x over previous
//
#include <hip/hip_runtime.h>
#include <stdint.h>

#define T_TOK 8192
#define DIM   1024
#define NE    8
#define NH    2816
#define NROWS (T_TOK*2)

typedef __attribute__((ext_vector_type(8))) __bf16 bf16x8;
typedef __attribute__((ext_vector_type(4))) float  f32x4;

typedef __attribute__((address_space(1))) const unsigned int g_as1;
typedef __attribute__((address_space(3))) unsigned int l_as3;
#define GLL(g, l) __builtin_amdgcn_global_load_lds((g_as1*)(g), (l_as3*)(l), 16, 0, 0)
#define MFMA16(a,b,c) __builtin_amdgcn_mfma_f32_16x16x32_bf16(a,b,c,0,0,0)

__device__ __forceinline__ unsigned short f2bf(float f){
  union { float f; uint32_t u; } v; v.f = f;
  uint32_t r = (v.u + 0x7FFFu + ((v.u >> 16) & 1u)) >> 16;
  return (unsigned short)r;
}

// ---------------- init / zero / convert ----------------

__global__ void init_k(int* counts, int* cursor){
  int i = threadIdx.x;
  if (i < NE){ counts[i] = 0; cursor[i] = 0; }
}

__global__ void zero_out_k(float4* __restrict__ out){
  int i = blockIdx.x*blockDim.x + threadIdx.x;
  const int n4 = T_TOK*DIM/4;
  const float4 z = make_float4(0.f,0.f,0.f,0.f);
  for (; i < n4; i += gridDim.x*blockDim.x) out[i] = z;
}

__global__ void cvt_k(const float* __restrict__ x, unsigned short* __restrict__ xbf){
  int i = blockIdx.x*blockDim.x + threadIdx.x;
  const int total = T_TOK*DIM/8;
  for (; i < total; i += gridDim.x*blockDim.x){
    const float4 a = *(const float4*)(x + (size_t)i*8);
    const float4 b = *(const float4*)(x + (size_t)i*8 + 4);
    ushort4 lo = make_ushort4(f2bf(a.x), f2bf(a.y), f2bf(a.z), f2bf(a.w));
    ushort4 hi = make_ushort4(f2bf(b.x), f2bf(b.y), f2bf(b.z), f2bf(b.w));
    *(ushort4*)(xbf + (size_t)i*8)     = lo;
    *(ushort4*)(xbf + (size_t)i*8 + 4) = hi;
  }
}

// transpose-convert: f32 [R][C] -> bf16 [C][R]
__global__ __launch_bounds__(256) void transp_k(const float* __restrict__ in,
    unsigned short* __restrict__ outp, int R, int C)
{
  __shared__ unsigned short Tl[64*68];
  const int r0 = blockIdx.x*64, c0 = blockIdx.y*64;
  const size_t mbase = (size_t)blockIdx.z * (size_t)R * (size_t)C;
  const float* ip = in + mbase;
  unsigned short* op = outp + mbase;
  const int t = threadIdx.x;
  #pragma unroll
  for (int i=0;i<4;i++){
    const int r  = (t>>4) + i*16;
    const int cq = t & 15;
    const float4 v = *(const float4*)(ip + (size_t)(r0+r)*C + c0 + cq*4);
    Tl[(cq*4+0)*68 + r] = f2bf(v.x);
    Tl[(cq*4+1)*68 + r] = f2bf(v.y);
    Tl[(cq*4+2)*68 + r] = f2bf(v.z);
    Tl[(cq*4+3)*68 + r] = f2bf(v.w);
  }
  __syncthreads();
  #pragma unroll
  for (int i=0;i<4;i++){
    const int idx = i*1024 + t*4;
    const int c = idx>>6, r = idx&63;
    const ushort4 v = *(const ushort4*)&Tl[c*68 + r];
    *(ushort4*)(op + (size_t)(c0+c)*R + r0 + r) = v;
  }
}

// fused w1+w3 transpose: z in [0,2*NE)
__global__ __launch_bounds__(256) void transp2_k(const float* __restrict__ w1,
    const float* __restrict__ w3, unsigned short* __restrict__ w1t,
    unsigned short* __restrict__ w3t)
{
  __shared__ unsigned short Tl[64*68];
  const int r0 = blockIdx.x*64, c0 = blockIdx.y*64;
  const int z = blockIdx.z;
  const size_t mbase = (size_t)(z & (NE-1)) * (size_t)DIM * (size_t)NH;
  const float* ip = (z < NE ? w1 : w3) + mbase;
  unsigned short* op = (z < NE ? w1t : w3t) + mbase;
  const int t = threadIdx.x;
  #pragma unroll
  for (int i=0;i<4;i++){
    const int r  = (t>>4) + i*16;
    const int cq = t & 15;
    const float4 v = *(const float4*)(ip + (size_t)(r0+r)*NH + c0 + cq*4);
    Tl[(cq*4+0)*68 + r] = f2bf(v.x);
    Tl[(cq*4+1)*68 + r] = f2bf(v.y);
    Tl[(cq*4+2)*68 + r] = f2bf(v.z);
    Tl[(cq*4+3)*68 + r] = f2bf(v.w);
  }
  __syncthreads();
  #pragma unroll
  for (int i=0;i<4;i++){
    const int idx = i*1024 + t*4;
    const int c = idx>>6, r = idx&63;
    const ushort4 v = *(const ushort4*)&Tl[c*68 + r];
    *(ushort4*)(op + (size_t)(c0+c)*DIM + r0 + r) = v;
  }
}

// ---------------- router ----------------

__global__ void router_k(const float* __restrict__ x, const float* __restrict__ rw,
                         int* __restrict__ topk_e, float* __restrict__ topk_w,
                         int* __restrict__ counts){
  const int t = blockIdx.x;
  const int l = threadIdx.x;
  const float* xr = x + (size_t)t * DIM;
  float acc[NE];
  #pragma unroll
  for (int e=0;e<NE;e++) acc[e] = 0.f;
  #pragma unroll
  for (int i=0;i<DIM/64;i++){
    float xv = xr[l + 64*i];
    #pragma unroll
    for (int e=0;e<NE;e++) acc[e] += xv * rw[e*DIM + l + 64*i];
  }
  #pragma unroll
  for (int e=0;e<NE;e++){
    float v = acc[e];
    #pragma unroll
    for (int off=32; off; off>>=1) v += __shfl_xor(v, off);
    acc[e] = v;
  }
  if (l == 0){
    int e0 = 0; float v0 = acc[0];
    #pragma unroll
    for (int e=1;e<NE;e++) if (acc[e] > v0){ v0 = acc[e]; e0 = e; }
    int e1 = -1; float v1 = -1e30f;
    #pragma unroll
    for (int e=0;e<NE;e++) if (e != e0 && acc[e] > v1){ v1 = acc[e]; e1 = e; }
    float ex = __expf(v1 - v0);
    float s  = 1.f + ex;
    topk_e[t*2]   = e0;  topk_e[t*2+1] = e1;
    topk_w[t*2]   = 1.f/s; topk_w[t*2+1] = ex/s;
    atomicAdd(&counts[e0], 1);
    atomicAdd(&counts[e1], 1);
  }
}

__global__ void prefix_k(const int* __restrict__ counts, int* __restrict__ offs){
  if (threadIdx.x == 0 && blockIdx.x == 0){
    int s = 0;
    for (int e=0;e<NE;e++){ offs[e] = s; s += counts[e]; }
  }
}

__global__ void scatter_k(const int* __restrict__ topk_e, const float* __restrict__ topk_w,
                          const int* __restrict__ offs, int* __restrict__ cursor,
                          int* __restrict__ row_tok, float* __restrict__ row_w){
  int t = blockIdx.x*blockDim.x + threadIdx.x;
  if (t >= T_TOK) return;
  #pragma unroll
  for (int k=0;k<2;k++){
    int e = topk_e[t*2+k];
    int p = atomicAdd(&cursor[e], 1);
    int flat = offs[e] + p;
    row_tok[flat] = t;
    row_w[flat]   = topk_w[t*2+k];
  }
}

// ============ FAST GEMMs: ring-3 LDS, counted vmcnt, swizzle, L2 grid ============
// Register law (r2-r8): 64 VGPR + 64 AGPR = 128/wave -> 4 waves/SIMD, 2 blocks/CU.
// Swizzle (BK=32): chunk ^= (row>>1)&3 on GLL source + ds_read (0 conflicts, r6).

// GEMM1 (round-6 proven, 260us/727TF): 128x128x2 tile, 8 waves (2x4), BK=32
__global__ __launch_bounds__(512,2) void gemm1_p(
    const unsigned short* __restrict__ xbf,
    const unsigned short* __restrict__ w1t, const unsigned short* __restrict__ w3t,
    unsigned short* __restrict__ hbuf,
    const int* __restrict__ row_tok,
    const int* __restrict__ counts, const int* __restrict__ offs)
{
  __shared__ unsigned short As [3][128*32];   // 24 KB
  __shared__ unsigned short B1s[3][128*32];   // 24 KB
  __shared__ unsigned short B3s[3][128*32];   // 24 KB  -> 72 KB, 2 blocks/CU

  const int i   = blockIdx.y*64 + blockIdx.x;
  const int lid = (i & 7)*1408 + (i >> 3);
  const int e   = lid / 1408;
  const int rem = lid - e*1408;
  const int h0  = (rem >> 6) * 128;
  const int rb  = rem & 63;

  const int cnt = counts[e];
  const int row0 = rb * 128;
  if (row0 >= cnt) return;
  const int nv   = min(128, cnt - row0);
  const int base = offs[e] + row0;
  const int NK   = DIM/32;

  const int t = threadIdx.x;
  const int r_loc = t >> 2, sct = t & 3;
  const int csw = (sct ^ ((r_loc >> 1) & 3)) * 8;
  const int tok = row_tok[base + min(r_loc, nv-1)];
  const unsigned short* aS  = xbf + (size_t)tok*DIM + csw;
  const unsigned short* b1S = w1t + ((size_t)(e*NH + h0) + r_loc)*DIM + csw;
  const unsigned short* b3S = w3t + ((size_t)(e*NH + h0) + r_loc)*DIM + csw;
  const int lo = t*16;

  const int wid = t >> 6, l = t & 63;
  const int wr = wid >> 2, wc = wid & 3;
  const int lr = l & 15,  lk = l >> 4;
  const int rc = (lk ^ ((lr >> 1) & 3)) * 8;

  f32x4 acc1[4][2], acc3[4][2];
  #pragma unroll
  for (int m=0;m<4;m++)
    #pragma unroll
    for (int n=0;n<2;n++){ acc1[m][n] = (f32x4)0.f; acc3[m][n] = (f32x4)0.f; }

  GLL(aS,    (char*)As[0]+lo); GLL(b1S,    (char*)B1s[0]+lo); GLL(b3S,    (char*)B3s[0]+lo);
  GLL(aS+32, (char*)As[1]+lo); GLL(b1S+32, (char*)B1s[1]+lo); GLL(b3S+32, (char*)B3s[1]+lo);

  for (int kt=0; kt<NK; ++kt){
    if (kt < NK-1) asm volatile("s_waitcnt vmcnt(3)" ::: "memory");
    else           asm volatile("s_waitcnt vmcnt(0)" ::: "memory");
    __builtin_amdgcn_s_barrier();

    if (kt+2 < NK){
      const int kA = (kt+2)*32;
      char* ad  = (char*)As [(kt+2)%3];
      char* b1d = (char*)B1s[(kt+2)%3];
      char* b3d = (char*)B3s[(kt+2)%3];
      GLL(aS+kA, ad+lo); GLL(b1S+kA, b1d+lo); GLL(b3S+kA, b3d+lo);
    }

    const unsigned short* Ab  = As [kt%3];
    const unsigned short* B1b = B1s[kt%3];
    const unsigned short* B3b = B3s[kt%3];

    bf16x8 a[4], b1[2], b3[2];
    #pragma unroll
    for (int m=0;m<4;m++) a[m] = *(const bf16x8*)&Ab[(wr*64 + m*16 + lr)*32 + rc];
    #pragma unroll
    for (int n=0;n<2;n++){
      b1[n] = *(const bf16x8*)&B1b[(wc*32 + n*16 + lr)*32 + rc];
      b3[n] = *(const bf16x8*)&B3b[(wc*32 + n*16 + lr)*32 + rc];
    }
    __builtin_amdgcn_s_setprio(1);
    #pragma unroll
    for (int m=0;m<4;m++)
      #pragma unroll
      for (int n=0;n<2;n++){
        acc1[m][n] = MFMA16(a[m], b1[n], acc1[m][n]);
        acc3[m][n] = MFMA16(a[m], b3[n], acc3[m][n]);
      }
    __builtin_amdgcn_s_setprio(0);
  }

  #pragma unroll
  for (int m=0;m<4;m++){
    #pragma unroll
    for (int i2=0;i2<4;i2++){
      const int r = wr*64 + m*16 + lk*4 + i2;
      if (r < nv){
        const size_t rowbase = (size_t)(base + r) * NH;
        #pragma unroll
        for (int n=0;n<2;n++){
          float z  = acc1[m][n][i2];
          float p3 = acc3[m][n][i2];
          float hv = (z / (1.f + __expf(-z))) * p3;
          hbuf[rowbase + h0 + wc*32 + n*16 + lr] = f2bf(hv);
        }
      }
    }
  }
}

// GEMM2 NEW: out += rw*(H@W2). Tile 128x256, wave = 64x64 out (16 MFMA / 8 reads),
// same register profile as gemm1_p (64 VGPR + 64 AGPR). BK=32, ring-3, vmcnt(3).
__global__ __launch_bounds__(512,2) void gemm2_r(
    const unsigned short* __restrict__ hbuf,
    const unsigned short* __restrict__ w2t,
    float* __restrict__ out,
    const int* __restrict__ row_tok, const float* __restrict__ row_w,
    const int* __restrict__ counts, const int* __restrict__ offs)
{
  __shared__ unsigned short As[3][128*32];   // 24 KB
  __shared__ unsigned short Bs[3][256*32];   // 48 KB  -> 72 KB, 2 blocks/CU

  // locality grid: 256 lids/expert = one expert per XCD; 4 d-tiles x 64 rb (safe range)
  const int i   = blockIdx.y*64 + blockIdx.x;     // grid (64,32)
  const int lid = (i & 7)*256 + (i >> 3);
  const int e   = lid >> 8;
  const int rem = lid & 255;
  const int d0  = (rem >> 6) * 256;               // 4 d-tiles of 256
  const int rb  = rem & 63;

  const int cnt  = counts[e];
  const int row0 = rb * 128;
  if (row0 >= cnt) return;
  const int nv   = min(128, cnt - row0);
  const int base = offs[e] + row0;
  const int NK   = NH/32;                         // 88

  const int t = threadIdx.x;
  const int r_loc = t >> 2, sct = t & 3;
  const int csw = (sct ^ ((r_loc >> 1) & 3)) * 8; // row+128 preserves XOR (128%8==0... (r>>1)&3 period 8 rows; 128%8==0 OK)
  const unsigned short* aS  = hbuf + (size_t)(base + min(r_loc, nv-1))*NH + csw;
  const unsigned short* bS0 = w2t + ((size_t)(e*DIM + d0) + r_loc)*NH + csw;
  const unsigned short* bS1 = bS0 + (size_t)128*NH;
  const int lo = t*16;

  const int wid = t >> 6, l = t & 63;
  const int wr = wid >> 2, wc = wid & 3;          // 2M x 4N; wave = 64 rows x 64 cols
  const int lr = l & 15,  lk = l >> 4;

  f32x4 acc[4][4];                                // 64 AGPR
  #pragma unroll
  for (int m=0;m<4;m++)
    #pragma unroll
    for (int n=0;n<4;n++) acc[m][n] = (f32x4)0.f;

  // prologue: tiles 0 and 1 (3 GLL each)
  GLL(aS,    (char*)As[0]+lo); GLL(bS0,    (char*)Bs[0]+lo); GLL(bS1,    (char*)Bs[0]+8192+lo);
  GLL(aS+32, (char*)As[1]+lo); GLL(bS0+32, (char*)Bs[1]+lo); GLL(bS1+32, (char*)Bs[1]+8192+lo);

  for (int kt=0; kt<NK; ++kt){
    if (kt < NK-1) asm volatile("s_waitcnt vmcnt(3)" ::: "memory");
    else           asm volatile("s_waitcnt vmcnt(0)" ::: "memory");
    __builtin_amdgcn_s_barrier();

    if (kt+2 < NK){
      const int kA = (kt+2)*32;
      char* ad = (char*)As[(kt+2)%3];
      char* bd = (char*)Bs[(kt+2)%3];
      GLL(aS+kA, ad+lo); GLL(bS0+kA, bd+lo); GLL(bS1+kA, bd+8192+lo);
    }

    const unsigned short* Ab = As[kt%3];
    const unsigned short* Bb = Bs[kt%3];

    bf16x8 a[4], b[4];
    #pragma unroll
    for (int m=0;m<4;m++){
      const int row = wr*64 + m*16 + lr;
      a[m] = *(const bf16x8*)&Ab[row*32 + ((lk ^ ((row>>1)&3))<<3)];
    }
    #pragma unroll
    for (int n=0;n<4;n++){
      const int row = wc*64 + n*16 + lr;
      b[n] = *(const bf16x8*)&Bb[row*32 + ((lk ^ ((row>>1)&3))<<3)];
    }
    __builtin_amdgcn_s_setprio(1);
    #pragma unroll
    for (int m=0;m<4;m++)
      #pragma unroll
      for (int n=0;n<4;n++)
        acc[m][n] = MFMA16(a[m], b[n], acc[m][n]);
    __builtin_amdgcn_s_setprio(0);
  }

  #pragma unroll
  for (int m=0;m<4;m++){
    #pragma unroll
    for (int i2=0;i2<4;i2++){
      const int r = wr*64 + m*16 + lk*4 + i2;
      if (r < nv){
        const int flat = base + r;
        const int tok  = row_tok[flat];
        const float wgt = row_w[flat];
        float* orow = out + (size_t)tok * DIM + d0 + wc*64;
        #pragma unroll
        for (int n=0;n<4;n++)
          atomicAdd(&orow[n*16 + lr], acc[m][n][i2] * wgt);
      }
    }
  }
}

// ============ SLOW FALLBACK (f32 weights, small ws) ============

__global__ __launch_bounds__(256) void gemm1_k(
    const unsigned short* __restrict__ xbf,
    const float* __restrict__ w1, const float* __restrict__ w3,
    unsigned short* __restrict__ hbuf,
    const int* __restrict__ row_tok,
    const int* __restrict__ counts, const int* __restrict__ offs)
{
  __shared__ unsigned short Al [128*32];
  __shared__ unsigned short B1l[128*32];
  __shared__ unsigned short B3l[128*32];
  const int e   = blockIdx.y >> 6;
  const int rb  = blockIdx.y & 63;
  const int cnt = counts[e];
  const int row0 = rb * 128;
  if (row0 >= cnt) return;
  const int nv   = min(128, cnt - row0);
  const int base = offs[e] + row0;
  const int h0   = blockIdx.x * 128;
  const int t  = threadIdx.x;
  const int ar0 = t >> 2;
  const int ac  = t & 3;
  const int tok0 = row_tok[base + min(ar0,      nv-1)];
  const int tok1 = row_tok[base + min(ar0 + 64, nv-1)];
  const size_t asrc0 = (size_t)tok0 * DIM + ac*8;
  const size_t asrc1 = (size_t)tok1 * DIM + ac*8;
  const int dg = t >> 5;
  const int hq = t & 31;
  const float* w1p = w1 + (size_t)e * DIM * NH + (size_t)(h0 + hq*4);
  const float* w3p = w3 + (size_t)e * DIM * NH + (size_t)(h0 + hq*4);
  const int wid = t >> 6, l = t & 63;
  const int wr = wid >> 1, wc = wid & 1;
  const int lr = l & 15,  lk = l >> 4;
  f32x4 acc1[4][4], acc3[4][4];
  #pragma unroll
  for (int m=0;m<4;m++)
    #pragma unroll
    for (int n=0;n<4;n++){ acc1[m][n] = (f32x4)0.f; acc3[m][n] = (f32x4)0.f; }
  for (int kk=0; kk<DIM/32; ++kk){
    const int k0 = kk*32;
    __syncthreads();
    *(uint4*)&Al[ar0*32 + ac*8]      = *(const uint4*)(xbf + asrc0 + k0);
    *(uint4*)&Al[(ar0+64)*32 + ac*8] = *(const uint4*)(xbf + asrc1 + k0);
    {
      const float4 f0 = *(const float4*)(w1p + (size_t)(k0 + dg*4 + 0)*NH);
      const float4 f1 = *(const float4*)(w1p + (size_t)(k0 + dg*4 + 1)*NH);
      const float4 f2 = *(const float4*)(w1p + (size_t)(k0 + dg*4 + 2)*NH);
      const float4 f3 = *(const float4*)(w1p + (size_t)(k0 + dg*4 + 3)*NH);
      const float* p0=(const float*)&f0; const float* p1=(const float*)&f1;
      const float* p2=(const float*)&f2; const float* p3=(const float*)&f3;
      #pragma unroll
      for (int j=0;j<4;j++){
        ushort4 pk = make_ushort4(f2bf(p0[j]), f2bf(p1[j]), f2bf(p2[j]), f2bf(p3[j]));
        *(ushort4*)&B1l[(hq*4+j)*32 + dg*4] = pk;
      }
      const float4 g0 = *(const float4*)(w3p + (size_t)(k0 + dg*4 + 0)*NH);
      const float4 g1 = *(const float4*)(w3p + (size_t)(k0 + dg*4 + 1)*NH);
      const float4 g2 = *(const float4*)(w3p + (size_t)(k0 + dg*4 + 2)*NH);
      const float4 g3 = *(const float4*)(w3p + (size_t)(k0 + dg*4 + 3)*NH);
      const float* q0=(const float*)&g0; const float* q1=(const float*)&g1;
      const float* q2=(const float*)&g2; const float* q3=(const float*)&g3;
      #pragma unroll
      for (int j=0;j<4;j++){
        ushort4 pk = make_ushort4(f2bf(q0[j]), f2bf(q1[j]), f2bf(q2[j]), f2bf(q3[j]));
        *(ushort4*)&B3l[(hq*4+j)*32 + dg*4] = pk;
      }
    }
    __syncthreads();
    bf16x8 a[4], b1[4], b3[4];
    #pragma unroll
    for (int m=0;m<4;m++) a[m] = *(const bf16x8*)&Al[(wr*64 + m*16 + lr)*32 + lk*8];
    #pragma unroll
    for (int n=0;n<4;n++){
      b1[n] = *(const bf16x8*)&B1l[(wc*64 + n*16 + lr)*32 + lk*8];
      b3[n] = *(const bf16x8*)&B3l[(wc*64 + n*16 + lr)*32 + lk*8];
    }
    #pragma unroll
    for (int m=0;m<4;m++)
      #pragma unroll
      for (int n=0;n<4;n++){
        acc1[m][n] = MFMA16(a[m], b1[n], acc1[m][n]);
        acc3[m][n] = MFMA16(a[m], b3[n], acc3[m][n]);
      }
  }
  #pragma unroll
  for (int m=0;m<4;m++){
    #pragma unroll
    for (int i=0;i<4;i++){
      const int r = wr*64 + m*16 + lk*4 + i;
      if (r < nv){
        const size_t rowbase = (size_t)(base + r) * NH;
        #pragma unroll
        for (int n=0;n<4;n++){
          float z  = acc1[m][n][i];
          float p3 = acc3[m][n][i];
          float hv = (z / (1.f + __expf(-z))) * p3;
          hbuf[rowbase + h0 + wc*64 + n*16 + lr] = f2bf(hv);
        }
      }
    }
  }
}

__global__ __launch_bounds__(256) void gemm2_k(
    const unsigned short* __restrict__ hbuf,
    const float* __restrict__ w2,
    float* __restrict__ out,
    const int* __restrict__ row_tok, const float* __restrict__ row_w,
    const int* __restrict__ counts, const int* __restrict__ offs)
{
  __shared__ unsigned short Al[128*32];
  __shared__ unsigned short Bl[128*32];
  const int e   = blockIdx.y >> 6;
  const int rb  = blockIdx.y & 63;
  const int cnt = counts[e];
  const int row0 = rb * 128;
  if (row0 >= cnt) return;
  const int nv   = min(128, cnt - row0);
  const int base = offs[e] + row0;
  const int d0   = blockIdx.x * 128;
  const int t  = threadIdx.x;
  const int ar0 = t >> 2;
  const int ac  = t & 3;
  const size_t asrc0 = (size_t)(base + min(ar0,      nv-1)) * NH + ac*8;
  const size_t asrc1 = (size_t)(base + min(ar0 + 64, nv-1)) * NH + ac*8;
  const int dg = t >> 5;
  const int hq = t & 31;
  const float* w2p = w2 + (size_t)e * NH * DIM + (size_t)(d0 + hq*4);
  const int wid = t >> 6, l = t & 63;
  const int wr = wid >> 1, wc = wid & 1;
  const int lr = l & 15,  lk = l >> 4;
  f32x4 acc[4][4];
  #pragma unroll
  for (int m=0;m<4;m++)
    #pragma unroll
    for (int n=0;n<4;n++) acc[m][n] = (f32x4)0.f;
  for (int kk=0; kk<NH/32; ++kk){
    const int k0 = kk*32;
    __syncthreads();
    *(uint4*)&Al[ar0*32 + ac*8]      = *(const uint4*)(hbuf + asrc0 + k0);
    *(uint4*)&Al[(ar0+64)*32 + ac*8] = *(const uint4*)(hbuf + asrc1 + k0);
    {
      const float4 f0 = *(const float4*)(w2p + (size_t)(k0 + dg*4 + 0)*DIM);
      const float4 f1 = *(const float4*)(w2p + (size_t)(k0 + dg*4 + 1)*DIM);
      const float4 f2 = *(const float4*)(w2p + (size_t)(k0 + dg*4 + 2)*DIM);
      const float4 f3 = *(const float4*)(w2p + (size_t)(k0 + dg*4 + 3)*DIM);
      const float* p0=(const float*)&f0; const float* p1=(const float*)&f1;
      const float* p2=(const float*)&f2; const float* p3=(const float*)&f3;
      #pragma unroll
      for (int j=0;j<4;j++){
        ushort4 pk = make_ushort4(f2bf(p0[j]), f2bf(p1[j]), f2bf(p2[j]), f2bf(p3[j]));
        *(ushort4*)&Bl[(hq*4+j)*32 + dg*4] = pk;
      }
    }
    __syncthreads();
    bf16x8 a[4], b[4];
    #pragma unroll
    for (int m=0;m<4;m++) a[m] = *(const bf16x8*)&Al[(wr*64 + m*16 + lr)*32 + lk*8];
    #pragma unroll
    for (int n=0;n<4;n++)  b[n] = *(const bf16x8*)&Bl[(wc*64 + n*16 + lr)*32 + lk*8];
    #pragma unroll
    for (int m=0;m<4;m++)
      #pragma unroll
      for (int n=0;n<4;n++)
        acc[m][n] = MFMA16(a[m], b[n], acc[m][n]);
  }
  #pragma unroll
  for (int m=0;m<4;m++){
    #pragma unroll
    for (int i=0;i<4;i++){
      const int r = wr*64 + m*16 + lk*4 + i;
      if (r < nv){
        const int flat = base + r;
        const int tok  = row_tok[flat];
        const float wgt = row_w[flat];
        float* orow = out + (size_t)tok * DIM + d0 + wc*64;
        #pragma unroll
        for (int n=0;n<4;n++)
          atomicAdd(&orow[n*16 + lr], acc[m][n][i] * wgt);
      }
    }
  }
}

// ---------------- launch ----------------

extern "C" void kernel_launch(void* const* d_in, const int* in_sizes, int n_in,
                              void* d_out, int out_size, void* d_ws, size_t ws_size,
                              hipStream_t stream) {
  (void)in_sizes; (void)n_in; (void)out_size;
  const float* x   = (const float*)d_in[0];
  const float* rw  = (const float*)d_in[1];
  const float* w1  = (const float*)d_in[2];
  const float* w2  = (const float*)d_in[3];
  const float* w3  = (const float*)d_in[4];
  float* out = (float*)d_out;
  char* ws = (char*)d_ws;

  const size_t SZ_XBF  = (size_t)T_TOK*DIM*2;
  const size_t SZ_HBUF = (size_t)NROWS*NH*2;
  const size_t SZ_WT   = (size_t)NE*NH*DIM*2;
  const size_t SZ_SMALL = (size_t)NROWS*4*2 + (size_t)T_TOK*2*4*2 + 3*64*4 + 4096;
  const size_t NEED_FAST = SZ_XBF + SZ_HBUF + 2*SZ_WT + SZ_SMALL;

  if (ws_size >= NEED_FAST) {
    size_t off = 0;
    unsigned short* xbf  = (unsigned short*)(ws + off); off += SZ_XBF;
    unsigned short* hbuf = (unsigned short*)(ws + off); off += SZ_HBUF;
    unsigned short* w1t  = (unsigned short*)(ws + off); off += SZ_WT;
    unsigned short* w3t  = (unsigned short*)(ws + off); off += SZ_WT;
    unsigned short* w2t  = w1t;  // w2t overlays w1t (dead after gemm1)
    int*   row_tok = (int*)  (ws + off); off += NROWS*4;
    float* row_w   = (float*)(ws + off); off += NROWS*4;
    int*   topk_e  = (int*)  (ws + off); off += T_TOK*2*4;
    float* topk_w  = (float*)(ws + off); off += T_TOK*2*4;
    int*   counts  = (int*)  (ws + off); off += 64;
    int*   offs    = (int*)  (ws + off); off += 64;
    int*   cursor  = (int*)  (ws + off); off += 64;

    init_k    <<<1, 64, 0, stream>>>(counts, cursor);
    zero_out_k<<<2048, 256, 0, stream>>>((float4*)out);
    cvt_k     <<<2048, 256, 0, stream>>>(x, xbf);
    router_k  <<<T_TOK, 64, 0, stream>>>(x, rw, topk_e, topk_w, counts);
    prefix_k  <<<1, 64, 0, stream>>>(counts, offs);
    scatter_k <<<(T_TOK+255)/256, 256, 0, stream>>>(topk_e, topk_w, offs, cursor, row_tok, row_w);
    transp2_k <<<dim3(DIM/64, NH/64, 2*NE), 256, 0, stream>>>(w1, w3, w1t, w3t);
    gemm1_p   <<<dim3(64, 176), 512, 0, stream>>>(xbf, w1t, w3t, hbuf, row_tok, counts, offs);
    transp_k  <<<dim3(NH/64, DIM/64, NE), 256, 0, stream>>>(w2, w2t, NH, DIM);
    gemm2_r   <<<dim3(64, 32), 512, 0, stream>>>(hbuf, w2t, out, row_tok, row_w, counts, offs);
  } else {
    size_t off = 0;
    unsigned short* xbf  = (unsigned short*)(ws + off); off += SZ_XBF;
    unsigned short* hbuf = (unsigned short*)(ws + off); off += SZ_HBUF;
    int*   row_tok = (int*)  (ws + off); off += NROWS*4;
    float* row_w   = (float*)(ws + off); off += NROWS*4;
    int*   topk_e  = (int*)  (ws + off); off += T_TOK*2*4;
    float* topk_w  = (float*)(ws + off); off += T_TOK*2*4;
    int*   counts  = (int*)  (ws + off); off += 64;
    int*   offs    = (int*)  (ws + off); off += 64;
    int*   cursor  = (int*)  (ws + off); off += 64;

    init_k    <<<1, 64, 0, stream>>>(counts, cursor);
    zero_out_k<<<2048, 256, 0, stream>>>((float4*)out);
    cvt_k     <<<2048, 256, 0, stream>>>(x, xbf);
    router_k  <<<T_TOK, 64, 0, stream>>>(x, rw, topk_e, topk_w, counts);
    prefix_k  <<<1, 64, 0, stream>>>(counts, offs);
    scatter_k <<<(T_TOK+255)/256, 256, 0, stream>>>(topk_e, topk_w, offs, cursor, row_tok, row_w);
    gemm1_k   <<<dim3(NH/128, NE*64), 256, 0, stream>>>(xbf, w1, w3, hbuf, row_tok, counts, offs);
    gemm2_k   <<<dim3(DIM/128, NE*64), 256, 0, stream>>>(hbuf, w2, out, row_tok, row_w, counts, offs);
  }
}

// Round 10
// 751.355 us; speedup vs baseline: 1.1867x; 1.1017x over previous
//
#include <hip/hip_runtime.h>
#include <stdint.h>

#define T_TOK 8192
#define DIM   1024
#define NE    8
#define NH    2816
#define NROWS (T_TOK*2)

typedef __attribute__((ext_vector_type(8))) __bf16 bf16x8;
typedef __attribute__((ext_vector_type(4))) float  f32x4;
typedef __attribute__((ext_vector_type(8))) unsigned short ushort8;

typedef __attribute__((address_space(1))) const unsigned int g_as1;
typedef __attribute__((address_space(3))) unsigned int l_as3;
#define GLL(g, l) __builtin_amdgcn_global_load_lds((g_as1*)(g), (l_as3*)(l), 16, 0, 0)
#define MFMA16(a,b,c) __builtin_amdgcn_mfma_f32_16x16x32_bf16(a,b,c,0,0,0)

__device__ __forceinline__ unsigned short f2bf(float f){
  union { float f; uint32_t u; } v; v.f = f;
  uint32_t r = (v.u + 0x7FFFu + ((v.u >> 16) & 1u)) >> 16;
  return (unsigned short)r;
}

// ---------------- zero+init (fused) ----------------

__global__ void zero_init_k(float4* __restrict__ out, int* counts, int* cursor){
  if (blockIdx.x == 0 && threadIdx.x < NE){ counts[threadIdx.x] = 0; cursor[threadIdx.x] = 0; }
  int i = blockIdx.x*blockDim.x + threadIdx.x;
  const int n4 = T_TOK*DIM/4;
  const float4 z = make_float4(0.f,0.f,0.f,0.f);
  for (; i < n4; i += gridDim.x*blockDim.x) out[i] = z;
}

__global__ void cvt_k(const float* __restrict__ x, unsigned short* __restrict__ xbf){
  int i = blockIdx.x*blockDim.x + threadIdx.x;
  const int total = T_TOK*DIM/8;
  for (; i < total; i += gridDim.x*blockDim.x){
    const float4 a = *(const float4*)(x + (size_t)i*8);
    const float4 b = *(const float4*)(x + (size_t)i*8 + 4);
    ushort4 lo = make_ushort4(f2bf(a.x), f2bf(a.y), f2bf(a.z), f2bf(a.w));
    ushort4 hi = make_ushort4(f2bf(b.x), f2bf(b.y), f2bf(b.z), f2bf(b.w));
    *(ushort4*)(xbf + (size_t)i*8)     = lo;
    *(ushort4*)(xbf + (size_t)i*8 + 4) = hi;
  }
}

// ---------------- fused transpose-convert: f32 [R][C] -> bf16 [C][R] ----------------
// z = zbase + blockIdx.y: z<8 -> w1[e=z]; z<16 -> w3[e=z-8]; z>=16 -> w2[e=z-16].
// 16B loads, 16B stores, pad-72 LDS (16B-aligned ushort8 rows, 2-way banks = free).

__global__ __launch_bounds__(256) void transpA_k(
    const float* __restrict__ w1, const float* __restrict__ w3,
    const float* __restrict__ w2,
    unsigned short* __restrict__ w1t, unsigned short* __restrict__ w3t,
    unsigned short* __restrict__ w2t, int zbase)
{
  __shared__ unsigned short Tl[64*72];
  const int z = zbase + blockIdx.y;
  const int f = blockIdx.x;                 // 704 flat tiles
  const size_t DS = (size_t)DIM*NH;
  const float* src; unsigned short* dst; int R, C, rt, ct;
  if (z < 16){
    R = DIM; C = NH; rt = f/44; ct = f - rt*44;
    const int e = z & 7;
    src = (z < 8 ? w1 : w3) + (size_t)e*DS;
    dst = (z < 8 ? w1t : w3t) + (size_t)e*DS;
  } else {
    R = NH; C = DIM; rt = f/16; ct = f - rt*16;
    const int e = z - 16;
    src = w2 + (size_t)e*DS;
    dst = w2t + (size_t)e*DS;
  }
  const int r0 = rt*64, c0 = ct*64;
  const int t = threadIdx.x;
  #pragma unroll
  for (int i=0;i<4;i++){
    const int r  = (t>>4) + i*16;
    const int cq = t & 15;
    const float4 v = *(const float4*)(src + (size_t)(r0+r)*C + c0 + cq*4);
    Tl[(cq*4+0)*72 + r] = f2bf(v.x);
    Tl[(cq*4+1)*72 + r] = f2bf(v.y);
    Tl[(cq*4+2)*72 + r] = f2bf(v.z);
    Tl[(cq*4+3)*72 + r] = f2bf(v.w);
  }
  __syncthreads();
  #pragma unroll
  for (int i=0;i<2;i++){
    const int c  = i*32 + (t>>3);
    const int r8 = (t&7)*8;
    const ushort8 v = *(const ushort8*)&Tl[c*72 + r8];
    *(ushort8*)(dst + (size_t)(c0+c)*R + r0 + r8) = v;
  }
}

// ---------------- router (fused with x->bf16 convert) ----------------

__global__ void router_k(const float* __restrict__ x, const float* __restrict__ rw,
                         unsigned short* __restrict__ xbf,
                         int* __restrict__ topk_e, float* __restrict__ topk_w,
                         int* __restrict__ counts){
  const int t = blockIdx.x;
  const int l = threadIdx.x;
  const float* xr = x + (size_t)t * DIM;
  unsigned short* xo = xbf + (size_t)t * DIM;
  float acc[NE];
  #pragma unroll
  for (int e=0;e<NE;e++) acc[e] = 0.f;
  #pragma unroll
  for (int i=0;i<4;i++){
    const int idx = l*4 + i*256;
    const float4 xv = *(const float4*)(xr + idx);
    ushort4 pk = make_ushort4(f2bf(xv.x), f2bf(xv.y), f2bf(xv.z), f2bf(xv.w));
    *(ushort4*)(xo + idx) = pk;
    #pragma unroll
    for (int e=0;e<NE;e++){
      const float4 wv = *(const float4*)(rw + e*DIM + idx);
      acc[e] += xv.x*wv.x + xv.y*wv.y + xv.z*wv.z + xv.w*wv.w;
    }
  }
  #pragma unroll
  for (int e=0;e<NE;e++){
    float v = acc[e];
    #pragma unroll
    for (int off=32; off; off>>=1) v += __shfl_xor(v, off);
    acc[e] = v;
  }
  if (l == 0){
    int e0 = 0; float v0 = acc[0];
    #pragma unroll
    for (int e=1;e<NE;e++) if (acc[e] > v0){ v0 = acc[e]; e0 = e; }
    int e1 = -1; float v1 = -1e30f;
    #pragma unroll
    for (int e=0;e<NE;e++) if (e != e0 && acc[e] > v1){ v1 = acc[e]; e1 = e; }
    float ex = __expf(v1 - v0);
    float s  = 1.f + ex;
    topk_e[t*2]   = e0;  topk_e[t*2+1] = e1;
    topk_w[t*2]   = 1.f/s; topk_w[t*2+1] = ex/s;
    atomicAdd(&counts[e0], 1);
    atomicAdd(&counts[e1], 1);
  }
}

__global__ void prefix_k(const int* __restrict__ counts, int* __restrict__ offs){
  if (threadIdx.x == 0 && blockIdx.x == 0){
    int s = 0;
    for (int e=0;e<NE;e++){ offs[e] = s; s += counts[e]; }
  }
}

__global__ void scatter_k(const int* __restrict__ topk_e, const float* __restrict__ topk_w,
                          const int* __restrict__ offs, int* __restrict__ cursor,
                          int* __restrict__ row_tok, float* __restrict__ row_w){
  int t = blockIdx.x*blockDim.x + threadIdx.x;
  if (t >= T_TOK) return;
  #pragma unroll
  for (int k=0;k<2;k++){
    int e = topk_e[t*2+k];
    int p = atomicAdd(&cursor[e], 1);
    int flat = offs[e] + p;
    row_tok[flat] = t;
    row_w[flat]   = topk_w[t*2+k];
  }
}

// ============ FAST GEMMs: ring-3 LDS, counted vmcnt, swizzle, L2 grid ============
// Register law (r2-r9): 64 VGPR + 64 AGPR = 128/wave -> 4 waves/SIMD, 2 blocks/CU,
// AND enough active blocks for backfill (gemm2 r9 lesson: 512 active = too few).

// GEMM1 (round-6 proven): 128x128x2 tile, 8 waves (2x4), BK=32, ring-3, vmcnt(3)
__global__ __launch_bounds__(512,2) void gemm1_p(
    const unsigned short* __restrict__ xbf,
    const unsigned short* __restrict__ w1t, const unsigned short* __restrict__ w3t,
    unsigned short* __restrict__ hbuf,
    const int* __restrict__ row_tok,
    const int* __restrict__ counts, const int* __restrict__ offs)
{
  __shared__ unsigned short As [3][128*32];
  __shared__ unsigned short B1s[3][128*32];
  __shared__ unsigned short B3s[3][128*32];   // 72 KB total

  const int i   = blockIdx.y*64 + blockIdx.x;
  const int lid = (i & 7)*1408 + (i >> 3);
  const int e   = lid / 1408;
  const int rem = lid - e*1408;
  const int h0  = (rem >> 6) * 128;
  const int rb  = rem & 63;

  const int cnt = counts[e];
  const int row0 = rb * 128;
  if (row0 >= cnt) return;
  const int nv   = min(128, cnt - row0);
  const int base = offs[e] + row0;
  const int NK   = DIM/32;

  const int t = threadIdx.x;
  const int r_loc = t >> 2, sct = t & 3;
  const int csw = (sct ^ ((r_loc >> 1) & 3)) * 8;
  const int tok = row_tok[base + min(r_loc, nv-1)];
  const unsigned short* aS  = xbf + (size_t)tok*DIM + csw;
  const unsigned short* b1S = w1t + ((size_t)(e*NH + h0) + r_loc)*DIM + csw;
  const unsigned short* b3S = w3t + ((size_t)(e*NH + h0) + r_loc)*DIM + csw;
  const int lo = t*16;

  const int wid = t >> 6, l = t & 63;
  const int wr = wid >> 2, wc = wid & 3;
  const int lr = l & 15,  lk = l >> 4;
  const int rc = (lk ^ ((lr >> 1) & 3)) * 8;

  f32x4 acc1[4][2], acc3[4][2];
  #pragma unroll
  for (int m=0;m<4;m++)
    #pragma unroll
    for (int n=0;n<2;n++){ acc1[m][n] = (f32x4)0.f; acc3[m][n] = (f32x4)0.f; }

  GLL(aS,    (char*)As[0]+lo); GLL(b1S,    (char*)B1s[0]+lo); GLL(b3S,    (char*)B3s[0]+lo);
  GLL(aS+32, (char*)As[1]+lo); GLL(b1S+32, (char*)B1s[1]+lo); GLL(b3S+32, (char*)B3s[1]+lo);

  for (int kt=0; kt<NK; ++kt){
    if (kt < NK-1) asm volatile("s_waitcnt vmcnt(3)" ::: "memory");
    else           asm volatile("s_waitcnt vmcnt(0)" ::: "memory");
    __builtin_amdgcn_s_barrier();

    if (kt+2 < NK){
      const int kA = (kt+2)*32;
      char* ad  = (char*)As [(kt+2)%3];
      char* b1d = (char*)B1s[(kt+2)%3];
      char* b3d = (char*)B3s[(kt+2)%3];
      GLL(aS+kA, ad+lo); GLL(b1S+kA, b1d+lo); GLL(b3S+kA, b3d+lo);
    }

    const unsigned short* Ab  = As [kt%3];
    const unsigned short* B1b = B1s[kt%3];
    const unsigned short* B3b = B3s[kt%3];

    bf16x8 a[4], b1[2], b3[2];
    #pragma unroll
    for (int m=0;m<4;m++) a[m] = *(const bf16x8*)&Ab[(wr*64 + m*16 + lr)*32 + rc];
    #pragma unroll
    for (int n=0;n<2;n++){
      b1[n] = *(const bf16x8*)&B1b[(wc*32 + n*16 + lr)*32 + rc];
      b3[n] = *(const bf16x8*)&B3b[(wc*32 + n*16 + lr)*32 + rc];
    }
    __builtin_amdgcn_s_setprio(1);
    #pragma unroll
    for (int m=0;m<4;m++)
      #pragma unroll
      for (int n=0;n<2;n++){
        acc1[m][n] = MFMA16(a[m], b1[n], acc1[m][n]);
        acc3[m][n] = MFMA16(a[m], b3[n], acc3[m][n]);
      }
    __builtin_amdgcn_s_setprio(0);
  }

  #pragma unroll
  for (int m=0;m<4;m++){
    #pragma unroll
    for (int i2=0;i2<4;i2++){
      const int r = wr*64 + m*16 + lk*4 + i2;
      if (r < nv){
        const size_t rowbase = (size_t)(base + r) * NH;
        #pragma unroll
        for (int n=0;n<2;n++){
          float z  = acc1[m][n][i2];
          float p3 = acc3[m][n][i2];
          float hv = (z / (1.f + __expf(-z))) * p3;
          hbuf[rowbase + h0 + wc*32 + n*16 + lr] = f2bf(hv);
        }
      }
    }
  }
}

// GEMM2 (round-6 proven): 128x128 tile, 8 waves (2x4), BK=32, ring-3, vmcnt(2)
__global__ __launch_bounds__(512,2) void gemm2_p(
    const unsigned short* __restrict__ hbuf,
    const unsigned short* __restrict__ w2t,
    float* __restrict__ out,
    const int* __restrict__ row_tok, const float* __restrict__ row_w,
    const int* __restrict__ counts, const int* __restrict__ offs)
{
  __shared__ unsigned short As[3][128*32];
  __shared__ unsigned short Bs[3][128*32];   // 48 KB

  const int i   = blockIdx.y*64 + blockIdx.x;     // grid (64, NE*8)
  const int lid = (i & 7)*512 + (i >> 3);
  const int e   = lid >> 9;
  const int rem = lid & 511;
  const int d0  = (rem >> 6) * 128;
  const int rb  = rem & 63;

  const int cnt = counts[e];
  const int row0 = rb * 128;
  if (row0 >= cnt) return;
  const int nv   = min(128, cnt - row0);
  const int base = offs[e] + row0;
  const int NK   = NH/32;

  const int t = threadIdx.x;
  const int r_loc = t >> 2, sct = t & 3;
  const int csw = (sct ^ ((r_loc >> 1) & 3)) * 8;
  const unsigned short* aS = hbuf + (size_t)(base + min(r_loc, nv-1))*NH + csw;
  const unsigned short* bS = w2t + ((size_t)(e*DIM + d0) + r_loc)*NH + csw;
  const int lo = t*16;

  const int wid = t >> 6, l = t & 63;
  const int wr = wid >> 2, wc = wid & 3;
  const int lr = l & 15,  lk = l >> 4;
  const int rc = (lk ^ ((lr >> 1) & 3)) * 8;

  f32x4 acc[4][2];
  #pragma unroll
  for (int m=0;m<4;m++)
    #pragma unroll
    for (int n=0;n<2;n++) acc[m][n] = (f32x4)0.f;

  GLL(aS,    (char*)As[0]+lo); GLL(bS,    (char*)Bs[0]+lo);
  GLL(aS+32, (char*)As[1]+lo); GLL(bS+32, (char*)Bs[1]+lo);

  for (int kt=0; kt<NK; ++kt){
    if (kt < NK-1) asm volatile("s_waitcnt vmcnt(2)" ::: "memory");
    else           asm volatile("s_waitcnt vmcnt(0)" ::: "memory");
    __builtin_amdgcn_s_barrier();

    if (kt+2 < NK){
      const int kA = (kt+2)*32;
      char* ad = (char*)As[(kt+2)%3];
      char* bd = (char*)Bs[(kt+2)%3];
      GLL(aS+kA, ad+lo); GLL(bS+kA, bd+lo);
    }

    const unsigned short* Ab = As[kt%3];
    const unsigned short* Bb = Bs[kt%3];

    bf16x8 a[4], b[2];
    #pragma unroll
    for (int m=0;m<4;m++) a[m] = *(const bf16x8*)&Ab[(wr*64 + m*16 + lr)*32 + rc];
    #pragma unroll
    for (int n=0;n<2;n++)  b[n] = *(const bf16x8*)&Bb[(wc*32 + n*16 + lr)*32 + rc];
    __builtin_amdgcn_s_setprio(1);
    #pragma unroll
    for (int m=0;m<4;m++)
      #pragma unroll
      for (int n=0;n<2;n++)
        acc[m][n] = MFMA16(a[m], b[n], acc[m][n]);
    __builtin_amdgcn_s_setprio(0);
  }

  #pragma unroll
  for (int m=0;m<4;m++){
    #pragma unroll
    for (int i2=0;i2<4;i2++){
      const int r = wr*64 + m*16 + lk*4 + i2;
      if (r < nv){
        const int flat = base + r;
        const int tok  = row_tok[flat];
        const float wgt = row_w[flat];
        float* orow = out + (size_t)tok * DIM + d0 + wc*32;
        #pragma unroll
        for (int n=0;n<2;n++)
          atomicAdd(&orow[n*16 + lr], acc[m][n][i2] * wgt);
      }
    }
  }
}

// ============ SLOW FALLBACK (f32 weights, small ws) ============

__global__ __launch_bounds__(256) void gemm1_k(
    const unsigned short* __restrict__ xbf,
    const float* __restrict__ w1, const float* __restrict__ w3,
    unsigned short* __restrict__ hbuf,
    const int* __restrict__ row_tok,
    const int* __restrict__ counts, const int* __restrict__ offs)
{
  __shared__ unsigned short Al [128*32];
  __shared__ unsigned short B1l[128*32];
  __shared__ unsigned short B3l[128*32];
  const int e   = blockIdx.y >> 6;
  const int rb  = blockIdx.y & 63;
  const int cnt = counts[e];
  const int row0 = rb * 128;
  if (row0 >= cnt) return;
  const int nv   = min(128, cnt - row0);
  const int base = offs[e] + row0;
  const int h0   = blockIdx.x * 128;
  const int t  = threadIdx.x;
  const int ar0 = t >> 2;
  const int ac  = t & 3;
  const int tok0 = row_tok[base + min(ar0,      nv-1)];
  const int tok1 = row_tok[base + min(ar0 + 64, nv-1)];
  const size_t asrc0 = (size_t)tok0 * DIM + ac*8;
  const size_t asrc1 = (size_t)tok1 * DIM + ac*8;
  const int dg = t >> 5;
  const int hq = t & 31;
  const float* w1p = w1 + (size_t)e * DIM * NH + (size_t)(h0 + hq*4);
  const float* w3p = w3 + (size_t)e * DIM * NH + (size_t)(h0 + hq*4);
  const int wid = t >> 6, l = t & 63;
  const int wr = wid >> 1, wc = wid & 1;
  const int lr = l & 15,  lk = l >> 4;
  f32x4 acc1[4][4], acc3[4][4];
  #pragma unroll
  for (int m=0;m<4;m++)
    #pragma unroll
    for (int n=0;n<4;n++){ acc1[m][n] = (f32x4)0.f; acc3[m][n] = (f32x4)0.f; }
  for (int kk=0; kk<DIM/32; ++kk){
    const int k0 = kk*32;
    __syncthreads();
    *(uint4*)&Al[ar0*32 + ac*8]      = *(const uint4*)(xbf + asrc0 + k0);
    *(uint4*)&Al[(ar0+64)*32 + ac*8] = *(const uint4*)(xbf + asrc1 + k0);
    {
      const float4 f0 = *(const float4*)(w1p + (size_t)(k0 + dg*4 + 0)*NH);
      const float4 f1 = *(const float4*)(w1p + (size_t)(k0 + dg*4 + 1)*NH);
      const float4 f2 = *(const float4*)(w1p + (size_t)(k0 + dg*4 + 2)*NH);
      const float4 f3 = *(const float4*)(w1p + (size_t)(k0 + dg*4 + 3)*NH);
      const float* p0=(const float*)&f0; const float* p1=(const float*)&f1;
      const float* p2=(const float*)&f2; const float* p3=(const float*)&f3;
      #pragma unroll
      for (int j=0;j<4;j++){
        ushort4 pk = make_ushort4(f2bf(p0[j]), f2bf(p1[j]), f2bf(p2[j]), f2bf(p3[j]));
        *(ushort4*)&B1l[(hq*4+j)*32 + dg*4] = pk;
      }
      const float4 g0 = *(const float4*)(w3p + (size_t)(k0 + dg*4 + 0)*NH);
      const float4 g1 = *(const float4*)(w3p + (size_t)(k0 + dg*4 + 1)*NH);
      const float4 g2 = *(const float4*)(w3p + (size_t)(k0 + dg*4 + 2)*NH);
      const float4 g3 = *(const float4*)(w3p + (size_t)(k0 + dg*4 + 3)*NH);
      const float* q0=(const float*)&g0; const float* q1=(const float*)&g1;
      const float* q2=(const float*)&g2; const float* q3=(const float*)&g3;
      #pragma unroll
      for (int j=0;j<4;j++){
        ushort4 pk = make_ushort4(f2bf(q0[j]), f2bf(q1[j]), f2bf(q2[j]), f2bf(q3[j]));
        *(ushort4*)&B3l[(hq*4+j)*32 + dg*4] = pk;
      }
    }
    __syncthreads();
    bf16x8 a[4], b1[4], b3[4];
    #pragma unroll
    for (int m=0;m<4;m++) a[m] = *(const bf16x8*)&Al[(wr*64 + m*16 + lr)*32 + lk*8];
    #pragma unroll
    for (int n=0;n<4;n++){
      b1[n] = *(const bf16x8*)&B1l[(wc*64 + n*16 + lr)*32 + lk*8];
      b3[n] = *(const bf16x8*)&B3l[(wc*64 + n*16 + lr)*32 + lk*8];
    }
    #pragma unroll
    for (int m=0;m<4;m++)
      #pragma unroll
      for (int n=0;n<4;n++){
        acc1[m][n] = MFMA16(a[m], b1[n], acc1[m][n]);
        acc3[m][n] = MFMA16(a[m], b3[n], acc3[m][n]);
      }
  }
  #pragma unroll
  for (int m=0;m<4;m++){
    #pragma unroll
    for (int i=0;i<4;i++){
      const int r = wr*64 + m*16 + lk*4 + i;
      if (r < nv){
        const size_t rowbase = (size_t)(base + r) * NH;
        #pragma unroll
        for (int n=0;n<4;n++){
          float z  = acc1[m][n][i];
          float p3 = acc3[m][n][i];
          float hv = (z / (1.f + __expf(-z))) * p3;
          hbuf[rowbase + h0 + wc*64 + n*16 + lr] = f2bf(hv);
        }
      }
    }
  }
}

__global__ __launch_bounds__(256) void gemm2_k(
    const unsigned short* __restrict__ hbuf,
    const float* __restrict__ w2,
    float* __restrict__ out,
    const int* __restrict__ row_tok, const float* __restrict__ row_w,
    const int* __restrict__ counts, const int* __restrict__ offs)
{
  __shared__ unsigned short Al[128*32];
  __shared__ unsigned short Bl[128*32];
  const int e   = blockIdx.y >> 6;
  const int rb  = blockIdx.y & 63;
  const int cnt = counts[e];
  const int row0 = rb * 128;
  if (row0 >= cnt) return;
  const int nv   = min(128, cnt - row0);
  const int base = offs[e] + row0;
  const int d0   = blockIdx.x * 128;
  const int t  = threadIdx.x;
  const int ar0 = t >> 2;
  const int ac  = t & 3;
  const size_t asrc0 = (size_t)(base + min(ar0,      nv-1)) * NH + ac*8;
  const size_t asrc1 = (size_t)(base + min(ar0 + 64, nv-1)) * NH + ac*8;
  const int dg = t >> 5;
  const int hq = t & 31;
  const float* w2p = w2 + (size_t)e * NH * DIM + (size_t)(d0 + hq*4);
  const int wid = t >> 6, l = t & 63;
  const int wr = wid >> 1, wc = wid & 1;
  const int lr = l & 15,  lk = l >> 4;
  f32x4 acc[4][4];
  #pragma unroll
  for (int m=0;m<4;m++)
    #pragma unroll
    for (int n=0;n<4;n++) acc[m][n] = (f32x4)0.f;
  for (int kk=0; kk<NH/32; ++kk){
    const int k0 = kk*32;
    __syncthreads();
    *(uint4*)&Al[ar0*32 + ac*8]      = *(const uint4*)(hbuf + asrc0 + k0);
    *(uint4*)&Al[(ar0+64)*32 + ac*8] = *(const uint4*)(hbuf + asrc1 + k0);
    {
      const float4 f0 = *(const float4*)(w2p + (size_t)(k0 + dg*4 + 0)*DIM);
      const float4 f1 = *(const float4*)(w2p + (size_t)(k0 + dg*4 + 1)*DIM);
      const float4 f2 = *(const float4*)(w2p + (size_t)(k0 + dg*4 + 2)*DIM);
      const float4 f3 = *(const float4*)(w2p + (size_t)(k0 + dg*4 + 3)*DIM);
      const float* p0=(const float*)&f0; const float* p1=(const float*)&f1;
      const float* p2=(const float*)&f2; const float* p3=(const float*)&f3;
      #pragma unroll
      for (int j=0;j<4;j++){
        ushort4 pk = make_ushort4(f2bf(p0[j]), f2bf(p1[j]), f2bf(p2[j]), f2bf(p3[j]));
        *(ushort4*)&Bl[(hq*4+j)*32 + dg*4] = pk;
      }
    }
    __syncthreads();
    bf16x8 a[4], b[4];
    #pragma unroll
    for (int m=0;m<4;m++) a[m] = *(const bf16x8*)&Al[(wr*64 + m*16 + lr)*32 + lk*8];
    #pragma unroll
    for (int n=0;n<4;n++)  b[n] = *(const bf16x8*)&Bl[(wc*64 + n*16 + lr)*32 + lk*8];
    #pragma unroll
    for (int m=0;m<4;m++)
      #pragma unroll
      for (int n=0;n<4;n++)
        acc[m][n] = MFMA16(a[m], b[n], acc[m][n]);
  }
  #pragma unroll
  for (int m=0;m<4;m++){
    #pragma unroll
    for (int i=0;i<4;i++){
      const int r = wr*64 + m*16 + lk*4 + i;
      if (r < nv){
        const int flat = base + r;
        const int tok  = row_tok[flat];
        const float wgt = row_w[flat];
        float* orow = out + (size_t)tok * DIM + d0 + wc*64;
        #pragma unroll
        for (int n=0;n<4;n++)
          atomicAdd(&orow[n*16 + lr], acc[m][n][i] * wgt);
      }
    }
  }
}

// ---------------- launch ----------------

extern "C" void kernel_launch(void* const* d_in, const int* in_sizes, int n_in,
                              void* d_out, int out_size, void* d_ws, size_t ws_size,
                              hipStream_t stream) {
  (void)in_sizes; (void)n_in; (void)out_size;
  const float* x   = (const float*)d_in[0];
  const float* rw  = (const float*)d_in[1];
  const float* w1  = (const float*)d_in[2];
  const float* w2  = (const float*)d_in[3];
  const float* w3  = (const float*)d_in[4];
  float* out = (float*)d_out;
  char* ws = (char*)d_ws;

  const size_t SZ_XBF  = (size_t)T_TOK*DIM*2;
  const size_t SZ_HBUF = (size_t)NROWS*NH*2;
  const size_t SZ_WT   = (size_t)NE*NH*DIM*2;
  const size_t SZ_SMALL = (size_t)NROWS*4*2 + (size_t)T_TOK*2*4*2 + 3*64*4 + 4096;
  const size_t NEED_FAST = SZ_XBF + SZ_HBUF + 2*SZ_WT + SZ_SMALL;
  const size_t NEED_FULL = SZ_XBF + SZ_HBUF + 3*SZ_WT + SZ_SMALL;

  if (ws_size >= NEED_FAST) {
    const bool full = (ws_size >= NEED_FULL);
    size_t off = 0;
    unsigned short* xbf  = (unsigned short*)(ws + off); off += SZ_XBF;
    unsigned short* hbuf = (unsigned short*)(ws + off); off += SZ_HBUF;
    unsigned short* w1t  = (unsigned short*)(ws + off); off += SZ_WT;
    unsigned short* w3t  = (unsigned short*)(ws + off); off += SZ_WT;
    unsigned short* w2t;
    if (full){ w2t = (unsigned short*)(ws + off); off += SZ_WT; }
    else      { w2t = w1t; }  // overlay (w1t dead after gemm1)
    int*   row_tok = (int*)  (ws + off); off += NROWS*4;
    float* row_w   = (float*)(ws + off); off += NROWS*4;
    int*   topk_e  = (int*)  (ws + off); off += T_TOK*2*4;
    float* topk_w  = (float*)(ws + off); off += T_TOK*2*4;
    int*   counts  = (int*)  (ws + off); off += 64;
    int*   offs    = (int*)  (ws + off); off += 64;
    int*   cursor  = (int*)  (ws + off); off += 64;

    zero_init_k<<<2048, 256, 0, stream>>>((float4*)out, counts, cursor);
    router_k   <<<T_TOK, 64, 0, stream>>>(x, rw, xbf, topk_e, topk_w, counts);
    prefix_k   <<<1, 64, 0, stream>>>(counts, offs);
    scatter_k  <<<(T_TOK+255)/256, 256, 0, stream>>>(topk_e, topk_w, offs, cursor, row_tok, row_w);
    if (full){
      transpA_k <<<dim3(704, 24), 256, 0, stream>>>(w1, w3, w2, w1t, w3t, w2t, 0);
      gemm1_p   <<<dim3(64, 176), 512, 0, stream>>>(xbf, w1t, w3t, hbuf, row_tok, counts, offs);
      gemm2_p   <<<dim3(64, NE*8), 512, 0, stream>>>(hbuf, w2t, out, row_tok, row_w, counts, offs);
    } else {
      transpA_k <<<dim3(704, 16), 256, 0, stream>>>(w1, w3, w2, w1t, w3t, w2t, 0);
      gemm1_p   <<<dim3(64, 176), 512, 0, stream>>>(xbf, w1t, w3t, hbuf, row_tok, counts, offs);
      transpA_k <<<dim3(704, 8), 256, 0, stream>>>(w1, w3, w2, w1t, w3t, w2t, 16);
      gemm2_p   <<<dim3(64, NE*8), 512, 0, stream>>>(hbuf, w2t, out, row_tok, row_w, counts, offs);
    }
  } else {
    size_t off = 0;
    unsigned short* xbf  = (unsigned short*)(ws + off); off += SZ_XBF;
    unsigned short* hbuf = (unsigned short*)(ws + off); off += SZ_HBUF;
    int*   row_tok = (int*)  (ws + off); off += NROWS*4;
    float* row_w   = (float*)(ws + off); off += NROWS*4;
    int*   topk_e  = (int*)  (ws + off); off += T_TOK*2*4;
    float* topk_w  = (float*)(ws + off); off += T_TOK*2*4;
    int*   counts  = (int*)  (ws + off); off += 64;
    int*   offs    = (int*)  (ws + off); off += 64;
    int*   cursor  = (int*)  (ws + off); off += 64;

    zero_init_k<<<2048, 256, 0, stream>>>((float4*)out, counts, cursor);
    router_k   <<<T_TOK, 64, 0, stream>>>(x, rw, xbf, topk_e, topk_w, counts);
    prefix_k   <<<1, 64, 0, stream>>>(counts, offs);
    scatter_k  <<<(T_TOK+255)/256, 256, 0, stream>>>(topk_e, topk_w, offs, cursor, row_tok, row_w);
    gemm1_k    <<<dim3(NH/128, NE*64), 256, 0, stream>>>(xbf, w1, w3, hbuf, row_tok, counts, offs);
    gemm2_k    <<<dim3(DIM/128, NE*64), 256, 0, stream>>>(hbuf, w2, out, row_tok, row_w, counts, offs);
  }
}